// Round 12
// baseline (422.740 us; speedup 1.0000x reference)
//
#include <hip/hip_runtime.h>
#include <hip/hip_fp16.h>

typedef _Float16 half8 __attribute__((ext_vector_type(8)));
typedef float f32x4 __attribute__((ext_vector_type(4)));

#define BUCKET_CAP 8192  // slots per bucket (256-node buckets; mean 4092, sd 64)

// ---------------------------------------------------------------- helpers

__device__ __forceinline__ unsigned pack_half2(float x, float y) {
    __half2 h = __float22half2_rn(make_float2(x, y));
    return *reinterpret_cast<unsigned*>(&h);
}
__device__ __forceinline__ float2 up2(unsigned u) {
    __half2 h = *reinterpret_cast<__half2*>(&u);
    return __half22float2(h);
}
__device__ __forceinline__ void acc8(float4& a, uint2 v) {
    float2 p = up2(v.x), q = up2(v.y);
    a.x += p.x; a.y += p.y; a.z += q.x; a.w += q.y;
}
__device__ __forceinline__ uint2 ld8(const char* __restrict__ b, unsigned off) {
    return *reinterpret_cast<const uint2*>(b + off);
}

// ---------------------------------------------------------------- fused init

__global__ __launch_bounds__(256) void k_wconv(const float* __restrict__ W1,
                                               const float* __restrict__ W2,
                                               __half* __restrict__ Wt1,
                                               __half* __restrict__ Wt2,
                                               int* __restrict__ bcnt, int nbz) {
    int i = blockIdx.x * 256 + threadIdx.x;
    if (i < nbz) bcnt[i] = 0;
    if (i < 16384) {
        int col = i >> 7, k = i & 127;
        Wt1[i] = __float2half(W1[(k << 7) + col]);
    } else if (i < 24576) {
        int j = i - 16384;
        int col = j >> 7, k = j & 127;
        Wt2[j] = __float2half(W2[(k << 6) + col]);
    }
}

// ------------------------------------------------ bucketed CSC construction
// Bucket = dst >> 8 (256 nodes, NB=391). Fixed-stride pair regions.
// Pair packed: src(24b) | dstLow8(8b).   [round-10 proven version]

__global__ __launch_bounds__(256) void k_bscatter2(const int* __restrict__ src,
                                                   const int* __restrict__ dst, int E,
                                                   int* __restrict__ bcnt,
                                                   unsigned* __restrict__ pairs,
                                                   int NB, int epb) {
    __shared__ int h[512];
    __shared__ int base[512];
    for (int i = threadIdx.x; i < NB; i += 256) h[i] = 0;
    __syncthreads();
    int lo = blockIdx.x * epb;
    int hi = min(lo + epb, E);
    for (int e = lo + threadIdx.x; e < hi; e += 256)
        atomicAdd(&h[dst[e] >> 8], 1);
    __syncthreads();
    for (int i = threadIdx.x; i < NB; i += 256) {
        int c = h[i];
        base[i] = c ? atomicAdd(&bcnt[i], c) : 0;
        h[i] = 0;
    }
    __syncthreads();
    for (int e = lo + threadIdx.x; e < hi; e += 256) {
        int s = src[e], d = dst[e];
        int b = d >> 8;
        int r = atomicAdd(&h[b], 1);
        pairs[(size_t)b * BUCKET_CAP + base[b] + r] =
            (unsigned)s | ((unsigned)(d & 255) << 24);
    }
}

__global__ __launch_bounds__(256) void k_bfinal2(const unsigned* __restrict__ pairs,
                                                 const int* __restrict__ bcnt,
                                                 float* __restrict__ dinv,
                                                 int* __restrict__ offs,
                                                 int* __restrict__ csc,
                                                 int n, int E, int NB) {
    __shared__ int cnt[256];
    __shared__ int scn[256];
    int b = blockIdx.x, t = threadIdx.x;

    int part = 0;
    for (int i = t; i < b; i += 256) part += bcnt[i];
    scn[t] = part;
    __syncthreads();
    for (int d = 128; d > 0; d >>= 1) {
        if (t < d) scn[t] += scn[t + d];
        __syncthreads();
    }
    int cbase = scn[0];
    int cnt_b = bcnt[b];
    __syncthreads();

    cnt[t] = 0;
    __syncthreads();
    size_t plo = (size_t)b * BUCKET_CAP;
    for (int e = t; e < cnt_b; e += 256)
        atomicAdd(&cnt[pairs[plo + e] >> 24], 1);
    __syncthreads();
    int c = cnt[t];
    int node = b * 256 + t;
    if (node < n) dinv[node] = rsqrtf((float)(c + 1));  // +1 self-loop
    scn[t] = c;
    __syncthreads();
    for (int d = 1; d < 256; d <<= 1) {
        int xv = (t >= d) ? scn[t - d] : 0;
        __syncthreads();
        scn[t] += xv;
        __syncthreads();
    }
    int myoff = cbase + scn[t] - c;
    if (node < n) offs[node] = myoff;
    if (b == NB - 1 && t == 255) offs[n] = E;
    cnt[t] = myoff;
    __syncthreads();
    for (int e = t; e < cnt_b; e += 256) {
        unsigned p = pairs[plo + e];
        int pos = atomicAdd(&cnt[p >> 24], 1);
        csc[pos] = (int)(p & 0x00FFFFFFu);
    }
}

// ---------------------------------------------------------------- MFMA GEMMs
// Intermediates SLICE-MAJOR: [slice][node][16 halfs] (32 B/node/slice).
// h1/out1: 8 slices (F=128). h2: 4 slices (F=64).

__global__ __launch_bounds__(256) void gemm1_mfma(const float* __restrict__ X,
                                                  const __half* __restrict__ Wt,  // [128][128] f16
                                                  const float* __restrict__ dinv,
                                                  __half* __restrict__ H, int nrows, int N) {
    __shared__ half8 wt[2048];  // 32 KB
    const int t = threadIdx.x;

    const half8* Wg = reinterpret_cast<const half8*>(Wt);
    for (int i = t; i < 2048; i += 256) {
        int col = i >> 4, kc = i & 15;
        wt[(col << 4) | (kc ^ (col & 7))] = Wg[i];
    }

    const int wid = t >> 6, lane = t & 63;
    const int li = lane & 15, kq = lane >> 4;
    const int rbase = blockIdx.x * 64 + wid * 16;
    int row = rbase + li;
    int rowc = min(row, nrows - 1);

    const f32x4* X4 = reinterpret_cast<const f32x4*>(X) + (size_t)rowc * 32;
    half8 a[4];
#pragma unroll
    for (int kk = 0; kk < 4; ++kk) {
        f32x4 lo = __builtin_nontemporal_load(&X4[kk * 8 + kq * 2]);
        f32x4 hi = __builtin_nontemporal_load(&X4[kk * 8 + kq * 2 + 1]);
        half8 v;
        v[0] = (_Float16)lo[0]; v[1] = (_Float16)lo[1];
        v[2] = (_Float16)lo[2]; v[3] = (_Float16)lo[3];
        v[4] = (_Float16)hi[0]; v[5] = (_Float16)hi[1];
        v[6] = (_Float16)hi[2]; v[7] = (_Float16)hi[3];
        a[kk] = v;
    }
    __syncthreads();

    f32x4 acc[8];
#pragma unroll
    for (int ct = 0; ct < 8; ++ct) acc[ct] = (f32x4){0.f, 0.f, 0.f, 0.f};

#pragma unroll
    for (int ct = 0; ct < 8; ++ct) {
        int col = ct * 16 + li;
        int cbase = col << 4, sw = col & 7;
#pragma unroll
        for (int kk = 0; kk < 4; ++kk) {
            half8 b = wt[cbase | ((kk * 4 + kq) ^ sw)];
            acc[ct] = __builtin_amdgcn_mfma_f32_16x16x32_f16(a[kk], b, acc[ct], 0, 0, 0);
        }
    }

    char* Hb = reinterpret_cast<char*>(H);
    const int r0 = rbase + kq * 4;
#pragma unroll
    for (int r = 0; r < 4; ++r) {
        int rr = r0 + r;
        if (rr < nrows) {
            float s = dinv[rr];
#pragma unroll
            for (int ct = 0; ct < 8; ++ct) {  // slice = ct
                size_t off = ((size_t)ct * N + rr) * 32 + li * 2;
                *reinterpret_cast<__half*>(Hb + off) = __float2half(acc[ct][r] * s);
            }
        }
    }
}

__global__ __launch_bounds__(256) void gemm2_mfma(const __half* __restrict__ Xh,  // 8-slice-major
                                                  const __half* __restrict__ Wt,  // [64][128] f16
                                                  const float* __restrict__ dinv,
                                                  __half* __restrict__ H,         // 4-slice-major
                                                  int nrows, int N) {
    __shared__ half8 wt[1024];  // 16 KB
    const int t = threadIdx.x;

    const half8* Wg = reinterpret_cast<const half8*>(Wt);
    for (int i = t; i < 1024; i += 256) {
        int col = i >> 4, kc = i & 15;
        wt[(col << 4) | (kc ^ (col & 7))] = Wg[i];
    }

    const int wid = t >> 6, lane = t & 63;
    const int li = lane & 15, kq = lane >> 4;
    const int rbase = blockIdx.x * 64 + wid * 16;
    int row = rbase + li;
    int rowc = min(row, nrows - 1);

    const char* Xb = reinterpret_cast<const char*>(Xh);
    half8 a[4];
#pragma unroll
    for (int kk = 0; kk < 4; ++kk) {
        int f0 = (kk * 4 + kq) * 8;
        size_t off = ((size_t)(f0 >> 4) * N + rowc) * 32 + (f0 & 15) * 2;
        a[kk] = *reinterpret_cast<const half8*>(Xb + off);
    }
    __syncthreads();

    f32x4 acc[4];
#pragma unroll
    for (int ct = 0; ct < 4; ++ct) acc[ct] = (f32x4){0.f, 0.f, 0.f, 0.f};

#pragma unroll
    for (int ct = 0; ct < 4; ++ct) {
        int col = ct * 16 + li;
        int cbase = col << 4, sw = col & 7;
#pragma unroll
        for (int kk = 0; kk < 4; ++kk) {
            half8 b = wt[cbase | ((kk * 4 + kq) ^ sw)];
            acc[ct] = __builtin_amdgcn_mfma_f32_16x16x32_f16(a[kk], b, acc[ct], 0, 0, 0);
        }
    }

    char* Hb = reinterpret_cast<char*>(H);
    const int r0 = rbase + kq * 4;
#pragma unroll
    for (int r = 0; r < 4; ++r) {
        int rr = r0 + r;
        if (rr < nrows) {
            float s = dinv[rr];
#pragma unroll
            for (int ct = 0; ct < 4; ++ct) {  // slice = ct
                size_t off = ((size_t)ct * N + rr) * 32 + li * 2;
                *reinterpret_cast<__half*>(Hb + off) = __float2half(acc[ct][r] * s);
            }
        }
    }
}

// ---------------------------------------------------------------- aggregation
// XCD-sliced, one WAVE per node, 16 edges/iteration.
// slice = bid&7 -> XCD affinity; slice data (3.2 MB) stays L2-resident.
// Lane l: edge e+(l>>2), bytes (l&3)*8 of the 32-B slice row -> every gather
// is one fully-used 32-B request. Butterfly shfl reduce. No LDS.

__global__ __launch_bounds__(256) void k_agg1s(const __half* __restrict__ h,   // 8-slice
                                               const int* __restrict__ offs,
                                               const int* __restrict__ csc,
                                               const float* __restrict__ dinv,
                                               const float* __restrict__ bias,
                                               __half* __restrict__ out,       // 8-slice
                                               int n, int N) {
    const int bid = blockIdx.x;
    const int slice = bid & 7;
    const int wid = (threadIdx.x >> 6);
    const int node = (bid >> 3) * 4 + wid;
    if (node >= n) return;
    const int lane = threadIdx.x & 63;
    const int eg = lane >> 2;       // edge group 0..15
    const int lb = lane & 3;        // 8-B chunk within 32-B row
    const unsigned loff = (unsigned)lb << 3;

    const char* hsl = reinterpret_cast<const char*>(h) + (size_t)slice * ((size_t)N * 32);
    int start = __builtin_amdgcn_readfirstlane(offs[node]);
    int end   = __builtin_amdgcn_readfirstlane(offs[node + 1]);

    float4 acc = make_float4(0.f, 0.f, 0.f, 0.f);
    for (int e = start; e < end; e += 16) {
        int ee = e + eg;
        bool valid = ee < end;
        int eec = valid ? ee : (end - 1);
        int idx = csc[eec];
        uint2 v = ld8(hsl, ((unsigned)idx << 5) | loff);
        if (!valid) { v.x = 0u; v.y = 0u; }
        acc8(acc, v);
    }
    if (eg == 0) acc8(acc, ld8(hsl, ((unsigned)node << 5) | loff));  // self loop

#pragma unroll
    for (int m = 4; m <= 32; m <<= 1) {
        acc.x += __shfl_xor(acc.x, m);
        acc.y += __shfl_xor(acc.y, m);
        acc.z += __shfl_xor(acc.z, m);
        acc.w += __shfl_xor(acc.w, m);
    }

    if (eg == 0) {
        float di = dinv[node];
        float4 bb = reinterpret_cast<const float4*>(bias)[slice * 4 + lb];
        uint2 o = make_uint2(
            pack_half2(fmaxf(fmaf(acc.x, di, bb.x), 0.f),
                       fmaxf(fmaf(acc.y, di, bb.y), 0.f)),
            pack_half2(fmaxf(fmaf(acc.z, di, bb.z), 0.f),
                       fmaxf(fmaf(acc.w, di, bb.w), 0.f)));
        *reinterpret_cast<uint2*>(reinterpret_cast<char*>(out) +
            ((size_t)slice * N + node) * 32 + loff) = o;
    }
}

// agg2: 4 feature-slices x 2 dst-halves = 8 virtual slices.
__global__ __launch_bounds__(256) void k_agg2s(const __half* __restrict__ h,   // 4-slice
                                               const int* __restrict__ offs,
                                               const int* __restrict__ csc,
                                               const float* __restrict__ dinv,
                                               const float* __restrict__ bias,
                                               float* __restrict__ out,        // row-major fp32
                                               int n, int N, int NH) {
    const int bid = blockIdx.x;
    const int vs = bid & 7;
    const int slice = vs & 3;
    const int half_ = vs >> 2;
    const int wid = (threadIdx.x >> 6);
    const int node = (bid >> 3) * 4 + wid + half_ * NH;
    if (node >= n || (bid >> 3) * 4 + wid >= NH) return;
    const int lane = threadIdx.x & 63;
    const int eg = lane >> 2;
    const int lb = lane & 3;
    const unsigned loff = (unsigned)lb << 3;

    const char* hsl = reinterpret_cast<const char*>(h) + (size_t)slice * ((size_t)N * 32);
    int start = __builtin_amdgcn_readfirstlane(offs[node]);
    int end   = __builtin_amdgcn_readfirstlane(offs[node + 1]);

    float4 acc = make_float4(0.f, 0.f, 0.f, 0.f);
    for (int e = start; e < end; e += 16) {
        int ee = e + eg;
        bool valid = ee < end;
        int eec = valid ? ee : (end - 1);
        int idx = csc[eec];
        uint2 v = ld8(hsl, ((unsigned)idx << 5) | loff);
        if (!valid) { v.x = 0u; v.y = 0u; }
        acc8(acc, v);
    }
    if (eg == 0) acc8(acc, ld8(hsl, ((unsigned)node << 5) | loff));  // self loop

#pragma unroll
    for (int m = 4; m <= 32; m <<= 1) {
        acc.x += __shfl_xor(acc.x, m);
        acc.y += __shfl_xor(acc.y, m);
        acc.z += __shfl_xor(acc.z, m);
        acc.w += __shfl_xor(acc.w, m);
    }

    if (eg == 0) {
        float di = dinv[node];
        float4 bb = reinterpret_cast<const float4*>(bias)[slice * 4 + lb];
        float4 o = make_float4(fmaf(acc.x, di, bb.x), fmaf(acc.y, di, bb.y),
                               fmaf(acc.z, di, bb.z), fmaf(acc.w, di, bb.w));
        reinterpret_cast<float4*>(out)[(size_t)node * 16 + slice * 4 + lb] = o;
    }
}

// ---------------------------------------------------------------- launch

extern "C" void kernel_launch(void* const* d_in, const int* in_sizes, int n_in,
                              void* d_out, int out_size, void* d_ws, size_t ws_size,
                              hipStream_t stream) {
    const float* x  = (const float*)d_in[0];
    const int*   ei = (const int*)d_in[1];
    const float* W1 = (const float*)d_in[2];
    const float* b1 = (const float*)d_in[3];
    const float* W2 = (const float*)d_in[4];
    const float* b2 = (const float*)d_in[5];
    float* out = (float*)d_out;

    const int n = in_sizes[0] / 128;   // 100000
    const int E = in_sizes[1] / 2;     // 1600000
    const int* src = ei;
    const int* dst = ei + E;
    const int NB = (n + 255) / 256;    // 391

    char* p = (char*)d_ws;
    auto carve = [&](size_t bytes) -> void* {
        void* r = (void*)p;
        p += (bytes + 255) & ~(size_t)255;
        return r;
    };
    float* dinv    = (float*)carve((size_t)n * 4);
    int*   offs    = (int*)carve((size_t)(n + 1) * 4);
    int*   bcnt    = (int*)carve((size_t)(NB + 1) * 4);
    __half* Wt1h   = (__half*)carve(16384 * 2);
    __half* Wt2h   = (__half*)carve(8192 * 2);
    int*   csc     = (int*)carve((size_t)E * 4);
    __half* h1     = (__half*)carve((size_t)n * 128 * 2);   // 25.6 MB (8-slice)
    __half* out1   = (__half*)carve((size_t)n * 128 * 2);   // 25.6 MB (8-slice)
    unsigned* pairs = (unsigned*)h1;  // 12.8 MB <= 25.6; dead before gemm1
    __half* h2     = h1;              // 4-slice, 12.8 MB; h1 dead after agg1

    const int gmm   = (n + 63) / 64;
    const int gagg1 = ((n + 3) / 4) * 8;             // 200000 blocks
    const int NH    = ((n + 7) / 8) * 4;             // dst-half size (50000)
    const int gagg2 = ((NH + 3) / 4) * 8;            // 100000 blocks
    const int GB    = 256;
    const int epb   = (E + GB - 1) / GB;

    // ---- init ----
    k_wconv<<<96, 256, 0, stream>>>(W1, W2, Wt1h, Wt2h, bcnt, NB + 1);

    // ---- CSC build ----
    k_bscatter2<<<GB, 256, 0, stream>>>(src, dst, E, bcnt, pairs, NB, epb);
    k_bfinal2<<<NB, 256, 0, stream>>>(pairs, bcnt, dinv, offs, csc, n, E, NB);

    // ---- layer 1 ----
    gemm1_mfma<<<gmm, 256, 0, stream>>>(x, Wt1h, dinv, h1, n, n);
    k_agg1s<<<gagg1, 256, 0, stream>>>(h1, offs, csc, dinv, b1, out1, n, n);

    // ---- layer 2 ----
    gemm2_mfma<<<gmm, 256, 0, stream>>>(out1, Wt2h, dinv, h2, n, n);
    k_agg2s<<<gagg2, 256, 0, stream>>>(h2, offs, csc, dinv, b2, out, n, n, NH);
}

// Round 13
// 215.785 us; speedup vs baseline: 1.9591x; 1.9591x over previous
//
#include <hip/hip_runtime.h>
#include <hip/hip_fp16.h>

typedef _Float16 half8 __attribute__((ext_vector_type(8)));
typedef float f32x4 __attribute__((ext_vector_type(4)));

#define BUCKET_CAP 8192  // slots per bucket (256-node buckets; mean 4092, sd 64)

// ---------------------------------------------------------------- helpers

__device__ __forceinline__ unsigned pack_half2(float x, float y) {
    __half2 h = __float22half2_rn(make_float2(x, y));
    return *reinterpret_cast<unsigned*>(&h);
}
__device__ __forceinline__ float2 up2(unsigned u) {
    __half2 h = *reinterpret_cast<__half2*>(&u);
    return __half22float2(h);
}
__device__ __forceinline__ void acc8(float4& a, uint2 v) {
    float2 p = up2(v.x), q = up2(v.y);
    a.x += p.x; a.y += p.y; a.z += q.x; a.w += q.y;
}
__device__ __forceinline__ void acc4(float2& a, unsigned v) {
    float2 p = up2(v);
    a.x += p.x; a.y += p.y;
}
__device__ __forceinline__ uint2 ld8(const char* __restrict__ b, unsigned off) {
    return *reinterpret_cast<const uint2*>(b + off);
}
__device__ __forceinline__ unsigned ld4(const char* __restrict__ b, unsigned off) {
    return *reinterpret_cast<const unsigned*>(b + off);
}

// ---------------------------------------------------------------- fused init

__global__ __launch_bounds__(256) void k_wconv(const float* __restrict__ W1,
                                               const float* __restrict__ W2,
                                               __half* __restrict__ Wt1,
                                               __half* __restrict__ Wt2,
                                               int* __restrict__ bcnt, int nbz) {
    int i = blockIdx.x * 256 + threadIdx.x;
    if (i < nbz) bcnt[i] = 0;
    if (i < 16384) {
        int col = i >> 7, k = i & 127;
        Wt1[i] = __float2half(W1[(k << 7) + col]);
    } else if (i < 24576) {
        int j = i - 16384;
        int col = j >> 7, k = j & 127;
        Wt2[j] = __float2half(W2[(k << 6) + col]);
    }
}

// ------------------------------------------------ bucketed CSC construction
// Bucket = dst >> 8 (256 nodes, NB=391). Fixed-stride pair regions.
// Pair packed: src(24b) | dstLow8(8b). GB=128 -> ~32-pair (128 B) runs per
// (block,bucket); nontemporal pair stores (write-once, read-once).

__global__ __launch_bounds__(256) void k_bscatter2(const int* __restrict__ src,
                                                   const int* __restrict__ dst, int E,
                                                   int* __restrict__ bcnt,
                                                   unsigned* __restrict__ pairs,
                                                   int NB, int epb) {
    __shared__ int h[512];
    __shared__ int base[512];
    for (int i = threadIdx.x; i < NB; i += 256) h[i] = 0;
    __syncthreads();
    int lo = blockIdx.x * epb;
    int hi = min(lo + epb, E);
    for (int e = lo + threadIdx.x; e < hi; e += 256)
        atomicAdd(&h[dst[e] >> 8], 1);
    __syncthreads();
    for (int i = threadIdx.x; i < NB; i += 256) {
        int c = h[i];
        base[i] = c ? atomicAdd(&bcnt[i], c) : 0;
        h[i] = 0;
    }
    __syncthreads();
    for (int e = lo + threadIdx.x; e < hi; e += 256) {
        int s = src[e], d = dst[e];
        int b = d >> 8;
        int r = atomicAdd(&h[b], 1);
        __builtin_nontemporal_store(
            (unsigned)s | ((unsigned)(d & 255) << 24),
            &pairs[(size_t)b * BUCKET_CAP + base[b] + r]);
    }
}

__global__ __launch_bounds__(256) void k_bfinal2(const unsigned* __restrict__ pairs,
                                                 const int* __restrict__ bcnt,
                                                 float* __restrict__ dinv,
                                                 int* __restrict__ offs,
                                                 int* __restrict__ csc,
                                                 int n, int E, int NB) {
    __shared__ int cnt[256];
    __shared__ int scn[256];
    int b = blockIdx.x, t = threadIdx.x;

    int part = 0;
    for (int i = t; i < b; i += 256) part += bcnt[i];
    scn[t] = part;
    __syncthreads();
    for (int d = 128; d > 0; d >>= 1) {
        if (t < d) scn[t] += scn[t + d];
        __syncthreads();
    }
    int cbase = scn[0];
    int cnt_b = bcnt[b];
    __syncthreads();

    cnt[t] = 0;
    __syncthreads();
    size_t plo = (size_t)b * BUCKET_CAP;
    for (int e = t; e < cnt_b; e += 256)
        atomicAdd(&cnt[pairs[plo + e] >> 24], 1);
    __syncthreads();
    int c = cnt[t];
    int node = b * 256 + t;
    if (node < n) dinv[node] = rsqrtf((float)(c + 1));  // +1 self-loop
    scn[t] = c;
    __syncthreads();
    for (int d = 1; d < 256; d <<= 1) {
        int xv = (t >= d) ? scn[t - d] : 0;
        __syncthreads();
        scn[t] += xv;
        __syncthreads();
    }
    int myoff = cbase + scn[t] - c;
    if (node < n) offs[node] = myoff;
    if (b == NB - 1 && t == 255) offs[n] = E;
    cnt[t] = myoff;
    __syncthreads();
    for (int e = t; e < cnt_b; e += 256) {
        unsigned p = pairs[plo + e];
        int pos = atomicAdd(&cnt[p >> 24], 1);
        csc[pos] = (int)(p & 0x00FFFFFFu);
    }
}

// ---------------------------------------------------------------- MFMA GEMMs
// mfma_f32_16x16x32_f16 layouts (gfx950). Block = 4 waves x 16 rows.
// W^T in LDS, XOR-swizzled by (col&7). Row-major fp16 intermediates.

__global__ __launch_bounds__(256) void gemm1_mfma(const float* __restrict__ X,
                                                  const __half* __restrict__ Wt,  // [128][128] f16
                                                  const float* __restrict__ dinv,
                                                  __half* __restrict__ H, int nrows) {
    __shared__ half8 wt[2048];  // 32 KB
    const int t = threadIdx.x;

    const half8* Wg = reinterpret_cast<const half8*>(Wt);
    for (int i = t; i < 2048; i += 256) {
        int col = i >> 4, kc = i & 15;
        wt[(col << 4) | (kc ^ (col & 7))] = Wg[i];
    }

    const int wid = t >> 6, lane = t & 63;
    const int li = lane & 15, kq = lane >> 4;
    const int rbase = blockIdx.x * 64 + wid * 16;
    int row = rbase + li;
    int rowc = min(row, nrows - 1);

    const f32x4* X4 = reinterpret_cast<const f32x4*>(X) + (size_t)rowc * 32;
    half8 a[4];
#pragma unroll
    for (int kk = 0; kk < 4; ++kk) {
        f32x4 lo = __builtin_nontemporal_load(&X4[kk * 8 + kq * 2]);
        f32x4 hi = __builtin_nontemporal_load(&X4[kk * 8 + kq * 2 + 1]);
        half8 v;
        v[0] = (_Float16)lo[0]; v[1] = (_Float16)lo[1];
        v[2] = (_Float16)lo[2]; v[3] = (_Float16)lo[3];
        v[4] = (_Float16)hi[0]; v[5] = (_Float16)hi[1];
        v[6] = (_Float16)hi[2]; v[7] = (_Float16)hi[3];
        a[kk] = v;
    }
    __syncthreads();

    f32x4 acc[8];
#pragma unroll
    for (int ct = 0; ct < 8; ++ct) acc[ct] = (f32x4){0.f, 0.f, 0.f, 0.f};

#pragma unroll
    for (int ct = 0; ct < 8; ++ct) {
        int col = ct * 16 + li;
        int cbase = col << 4, sw = col & 7;
#pragma unroll
        for (int kk = 0; kk < 4; ++kk) {
            half8 b = wt[cbase | ((kk * 4 + kq) ^ sw)];
            acc[ct] = __builtin_amdgcn_mfma_f32_16x16x32_f16(a[kk], b, acc[ct], 0, 0, 0);
        }
    }

    const int r0 = rbase + kq * 4;
#pragma unroll
    for (int r = 0; r < 4; ++r) {
        int rr = r0 + r;
        if (rr < nrows) {
            float s = dinv[rr];
            __half* orow = H + (size_t)rr * 128;
#pragma unroll
            for (int ct = 0; ct < 8; ++ct)
                orow[ct * 16 + li] = __float2half(acc[ct][r] * s);
        }
    }
}

__global__ __launch_bounds__(256) void gemm2_mfma(const __half* __restrict__ Xh,
                                                  const __half* __restrict__ Wt,  // [64][128] f16
                                                  const float* __restrict__ dinv,
                                                  __half* __restrict__ H, int nrows) {
    __shared__ half8 wt[1024];  // 16 KB
    const int t = threadIdx.x;

    const half8* Wg = reinterpret_cast<const half8*>(Wt);
    for (int i = t; i < 1024; i += 256) {
        int col = i >> 4, kc = i & 15;
        wt[(col << 4) | (kc ^ (col & 7))] = Wg[i];
    }

    const int wid = t >> 6, lane = t & 63;
    const int li = lane & 15, kq = lane >> 4;
    const int rbase = blockIdx.x * 64 + wid * 16;
    int row = rbase + li;
    int rowc = min(row, nrows - 1);

    const half8* A8 = reinterpret_cast<const half8*>(Xh) + (size_t)rowc * 16;
    half8 a[4];
#pragma unroll
    for (int kk = 0; kk < 4; ++kk) a[kk] = A8[kk * 4 + kq];
    __syncthreads();

    f32x4 acc[4];
#pragma unroll
    for (int ct = 0; ct < 4; ++ct) acc[ct] = (f32x4){0.f, 0.f, 0.f, 0.f};

#pragma unroll
    for (int ct = 0; ct < 4; ++ct) {
        int col = ct * 16 + li;
        int cbase = col << 4, sw = col & 7;
#pragma unroll
        for (int kk = 0; kk < 4; ++kk) {
            half8 b = wt[cbase | ((kk * 4 + kq) ^ sw)];
            acc[ct] = __builtin_amdgcn_mfma_f32_16x16x32_f16(a[kk], b, acc[ct], 0, 0, 0);
        }
    }

    const int r0 = rbase + kq * 4;
#pragma unroll
    for (int r = 0; r < 4; ++r) {
        int rr = r0 + r;
        if (rr < nrows) {
            float s = dinv[rr];
            __half* orow = H + (size_t)rr * 64;
#pragma unroll
            for (int ct = 0; ct < 4; ++ct)
                orow[ct * 16 + li] = __float2half(acc[ct][r] * s);
        }
    }
}

// ---------------------------------------------------------------- aggregation
// One wave per node; lanes 0-31 gather edge e, lanes 32-63 edge e+1.
// Scalar index loads via readfirstlane'd offsets; 32-bit saddr+voffset
// gathers; 8 edges (4 loads/lane) per main-loop iteration. [r6 measured best]

__global__ __launch_bounds__(256) void k_agg1(const __half* __restrict__ h,
                                              const int* __restrict__ offs,
                                              const int* __restrict__ csc,
                                              const float* __restrict__ dinv,
                                              const float* __restrict__ bias,
                                              __half* __restrict__ out, int n) {
    int node = (blockIdx.x * 256 + threadIdx.x) >> 6;
    if (node >= n) return;
    int lane = threadIdx.x & 63;
    int g = lane >> 5, li = lane & 31;            // li covers cols 4li..4li+3
    const char* hb = reinterpret_cast<const char*>(h);  // row = 256 B
    const unsigned loff = (unsigned)li << 3;
    int start = __builtin_amdgcn_readfirstlane(offs[node]);
    int end   = __builtin_amdgcn_readfirstlane(offs[node + 1]);
    float4 acc = make_float4(0.f, 0.f, 0.f, 0.f);

    int e = start;
    int emain = start + ((end - start) & ~7);
    for (; e < emain; e += 8) {
        int a0 = csc[e],     a1 = csc[e + 1], a2 = csc[e + 2], a3 = csc[e + 3];
        int a4 = csc[e + 4], a5 = csc[e + 5], a6 = csc[e + 6], a7 = csc[e + 7];
        unsigned o0 = (((unsigned)(g ? a1 : a0)) << 8) | loff;
        unsigned o1 = (((unsigned)(g ? a3 : a2)) << 8) | loff;
        unsigned o2 = (((unsigned)(g ? a5 : a4)) << 8) | loff;
        unsigned o3 = (((unsigned)(g ? a7 : a6)) << 8) | loff;
        uint2 v0 = ld8(hb, o0);
        uint2 v1 = ld8(hb, o1);
        uint2 v2 = ld8(hb, o2);
        uint2 v3 = ld8(hb, o3);
        acc8(acc, v0); acc8(acc, v1); acc8(acc, v2); acc8(acc, v3);
    }
    for (; e < end; e += 2) {
        int sa = csc[e];
        int sb = (e + 1 < end) ? csc[e + 1] : sa;
        unsigned o = (((unsigned)(g ? sb : sa)) << 8) | loff;
        uint2 v = ld8(hb, o);
        if (g && (e + 1 >= end)) { v.x = 0u; v.y = 0u; }
        acc8(acc, v);
    }
    acc.x += __shfl_xor(acc.x, 32);
    acc.y += __shfl_xor(acc.y, 32);
    acc.z += __shfl_xor(acc.z, 32);
    acc.w += __shfl_xor(acc.w, 32);
    uint2 vs = ld8(hb, (((unsigned)node) << 8) | loff);  // self loop
    acc8(acc, vs);
    float di = dinv[node];
    float4 bb = reinterpret_cast<const float4*>(bias)[li];
    float ox = fmaxf(fmaf(acc.x, di, bb.x), 0.f);
    float oy = fmaxf(fmaf(acc.y, di, bb.y), 0.f);
    float oz = fmaxf(fmaf(acc.z, di, bb.z), 0.f);
    float ow = fmaxf(fmaf(acc.w, di, bb.w), 0.f);
    if (g == 0)
        reinterpret_cast<uint2*>(out)[(size_t)node * 32 + li] =
            make_uint2(pack_half2(ox, oy), pack_half2(oz, ow));
}

__global__ __launch_bounds__(256) void k_agg2(const __half* __restrict__ h,
                                              const int* __restrict__ offs,
                                              const int* __restrict__ csc,
                                              const float* __restrict__ dinv,
                                              const float* __restrict__ bias,
                                              float* __restrict__ out, int n) {
    int node = (blockIdx.x * 256 + threadIdx.x) >> 6;
    if (node >= n) return;
    int lane = threadIdx.x & 63;
    int g = lane >> 5, li = lane & 31;            // li covers cols 2li..2li+1
    const char* hb = reinterpret_cast<const char*>(h);  // row = 128 B
    const unsigned loff = (unsigned)li << 2;
    int start = __builtin_amdgcn_readfirstlane(offs[node]);
    int end   = __builtin_amdgcn_readfirstlane(offs[node + 1]);
    float2 acc = make_float2(0.f, 0.f);

    int e = start;
    int emain = start + ((end - start) & ~7);
    for (; e < emain; e += 8) {
        int a0 = csc[e],     a1 = csc[e + 1], a2 = csc[e + 2], a3 = csc[e + 3];
        int a4 = csc[e + 4], a5 = csc[e + 5], a6 = csc[e + 6], a7 = csc[e + 7];
        unsigned o0 = (((unsigned)(g ? a1 : a0)) << 7) | loff;
        unsigned o1 = (((unsigned)(g ? a3 : a2)) << 7) | loff;
        unsigned o2 = (((unsigned)(g ? a5 : a4)) << 7) | loff;
        unsigned o3 = (((unsigned)(g ? a7 : a6)) << 7) | loff;
        unsigned v0 = ld4(hb, o0);
        unsigned v1 = ld4(hb, o1);
        unsigned v2 = ld4(hb, o2);
        unsigned v3 = ld4(hb, o3);
        acc4(acc, v0); acc4(acc, v1); acc4(acc, v2); acc4(acc, v3);
    }
    for (; e < end; e += 2) {
        int sa = csc[e];
        int sb = (e + 1 < end) ? csc[e + 1] : sa;
        unsigned o = (((unsigned)(g ? sb : sa)) << 7) | loff;
        unsigned v = ld4(hb, o);
        if (g && (e + 1 >= end)) v = 0u;
        acc4(acc, v);
    }
    acc.x += __shfl_xor(acc.x, 32);
    acc.y += __shfl_xor(acc.y, 32);
    acc4(acc, ld4(hb, (((unsigned)node) << 7) | loff));  // self loop
    float di = dinv[node];
    float2 bb = reinterpret_cast<const float2*>(bias)[li];
    if (g == 0)
        reinterpret_cast<float2*>(out)[(size_t)node * 32 + li] =
            make_float2(fmaf(acc.x, di, bb.x), fmaf(acc.y, di, bb.y));
}

// ---------------------------------------------------------------- launch

extern "C" void kernel_launch(void* const* d_in, const int* in_sizes, int n_in,
                              void* d_out, int out_size, void* d_ws, size_t ws_size,
                              hipStream_t stream) {
    const float* x  = (const float*)d_in[0];
    const int*   ei = (const int*)d_in[1];
    const float* W1 = (const float*)d_in[2];
    const float* b1 = (const float*)d_in[3];
    const float* W2 = (const float*)d_in[4];
    const float* b2 = (const float*)d_in[5];
    float* out = (float*)d_out;

    const int n = in_sizes[0] / 128;   // 100000 (< 2^24: packed pairs valid)
    const int E = in_sizes[1] / 2;     // 1600000
    const int* src = ei;
    const int* dst = ei + E;
    const int NB = (n + 255) / 256;    // 391 buckets of 256 nodes

    char* p = (char*)d_ws;
    auto carve = [&](size_t bytes) -> void* {
        void* r = (void*)p;
        p += (bytes + 255) & ~(size_t)255;
        return r;
    };
    float* dinv    = (float*)carve((size_t)n * 4);
    int*   offs    = (int*)carve((size_t)(n + 1) * 4);
    int*   bcnt    = (int*)carve((size_t)(NB + 1) * 4);
    __half* Wt1h   = (__half*)carve(16384 * 2);
    __half* Wt2h   = (__half*)carve(8192 * 2);
    int*   csc     = (int*)carve((size_t)E * 4);
    __half* h1     = (__half*)carve((size_t)n * 128 * 2);   // 25.6 MB
    __half* out1   = (__half*)carve((size_t)n * 128 * 2);   // 25.6 MB
    unsigned* pairs = (unsigned*)h1;  // 12.8 MB <= 25.6; dead before gemm1
    __half* h2     = h1;              // h1 dead after layer-1 aggregation

    const int gmm  = (n + 63) / 64;
    const int gagg = (n + 3) / 4;
    const int GB   = 128;                 // bucket-pass blocks (~32-pair runs)
    const int epb  = (E + GB - 1) / GB;   // 12500 edges per block

    // ---- init ----
    k_wconv<<<96, 256, 0, stream>>>(W1, W2, Wt1h, Wt2h, bcnt, NB + 1);

    // ---- CSC build ----
    k_bscatter2<<<GB, 256, 0, stream>>>(src, dst, E, bcnt, pairs, NB, epb);
    k_bfinal2<<<NB, 256, 0, stream>>>(pairs, bcnt, dinv, offs, csc, n, E, NB);

    // ---- layer 1: h1 = f16((x @ W1) * dinv) ; out1 = f16(relu(agg*dinv + b1)) ----
    gemm1_mfma<<<gmm, 256, 0, stream>>>(x, Wt1h, dinv, h1, n);
    k_agg1<<<gagg, 256, 0, stream>>>(h1, offs, csc, dinv, b1, out1, n);

    // ---- layer 2: h2 = f16((out1 @ W2) * dinv) ; out = agg*dinv + b2 ----
    gemm2_mfma<<<gmm, 256, 0, stream>>>(out1, Wt2h, dinv, h2, n);
    k_agg2<<<gagg, 256, 0, stream>>>(h2, offs, csc, dinv, b2, out, n);
}

// Round 14
// 182.588 us; speedup vs baseline: 2.3153x; 1.1818x over previous
//
#include <hip/hip_runtime.h>
#include <hip/hip_fp16.h>

typedef _Float16 half8 __attribute__((ext_vector_type(8)));
typedef float f32x4 __attribute__((ext_vector_type(4)));

#define BUCKET_CAP 8192  // slots per bucket (256-node buckets; mean 4092, sd 64)

// ---------------------------------------------------------------- helpers

__device__ __forceinline__ unsigned pack_half2(float x, float y) {
    __half2 h = __float22half2_rn(make_float2(x, y));
    return *reinterpret_cast<unsigned*>(&h);
}
__device__ __forceinline__ float2 up2(unsigned u) {
    __half2 h = *reinterpret_cast<__half2*>(&u);
    return __half22float2(h);
}
__device__ __forceinline__ void acc8(float4& a, uint2 v) {
    float2 p = up2(v.x), q = up2(v.y);
    a.x += p.x; a.y += p.y; a.z += q.x; a.w += q.y;
}
__device__ __forceinline__ void acc4(float2& a, unsigned v) {
    float2 p = up2(v);
    a.x += p.x; a.y += p.y;
}
__device__ __forceinline__ uint2 ld8(const char* __restrict__ b, unsigned off) {
    return *reinterpret_cast<const uint2*>(b + off);
}
__device__ __forceinline__ unsigned ld4(const char* __restrict__ b, unsigned off) {
    return *reinterpret_cast<const unsigned*>(b + off);
}

// ---------------------------------------------------------------- fused init

__global__ __launch_bounds__(256) void k_wconv(const float* __restrict__ W1,
                                               const float* __restrict__ W2,
                                               __half* __restrict__ Wt1,
                                               __half* __restrict__ Wt2,
                                               int* __restrict__ bcnt, int nbz) {
    int i = blockIdx.x * 256 + threadIdx.x;
    if (i < nbz) bcnt[i] = 0;
    if (i < 16384) {
        int col = i >> 7, k = i & 127;
        Wt1[i] = __float2half(W1[(k << 7) + col]);
    } else if (i < 24576) {
        int j = i - 16384;
        int col = j >> 7, k = j & 127;
        Wt2[j] = __float2half(W2[(k << 6) + col]);
    }
}

// ------------------------------------------------ bucketed CSC construction
// Bucket = dst >> 8 (256 nodes, NB=391). Fixed-stride pair regions.
// Pair packed: src(24b) | dstLow8(8b).
// [r10-exact: GB=256, plain cached stores. GB=128 -> 4% occupancy (r13);
//  nontemporal pair stores -> 71 MB HBM write amplification (r13).]

__global__ __launch_bounds__(256) void k_bscatter2(const int* __restrict__ src,
                                                   const int* __restrict__ dst, int E,
                                                   int* __restrict__ bcnt,
                                                   unsigned* __restrict__ pairs,
                                                   int NB, int epb) {
    __shared__ int h[512];
    __shared__ int base[512];
    for (int i = threadIdx.x; i < NB; i += 256) h[i] = 0;
    __syncthreads();
    int lo = blockIdx.x * epb;
    int hi = min(lo + epb, E);
    for (int e = lo + threadIdx.x; e < hi; e += 256)
        atomicAdd(&h[dst[e] >> 8], 1);
    __syncthreads();
    for (int i = threadIdx.x; i < NB; i += 256) {
        int c = h[i];
        base[i] = c ? atomicAdd(&bcnt[i], c) : 0;
        h[i] = 0;
    }
    __syncthreads();
    for (int e = lo + threadIdx.x; e < hi; e += 256) {
        int s = src[e], d = dst[e];
        int b = d >> 8;
        int r = atomicAdd(&h[b], 1);
        pairs[(size_t)b * BUCKET_CAP + base[b] + r] =
            (unsigned)s | ((unsigned)(d & 255) << 24);
    }
}

__global__ __launch_bounds__(256) void k_bfinal2(const unsigned* __restrict__ pairs,
                                                 const int* __restrict__ bcnt,
                                                 float* __restrict__ dinv,
                                                 int* __restrict__ offs,
                                                 int* __restrict__ csc,
                                                 int n, int E, int NB) {
    __shared__ int cnt[256];
    __shared__ int scn[256];
    int b = blockIdx.x, t = threadIdx.x;

    int part = 0;
    for (int i = t; i < b; i += 256) part += bcnt[i];
    scn[t] = part;
    __syncthreads();
    for (int d = 128; d > 0; d >>= 1) {
        if (t < d) scn[t] += scn[t + d];
        __syncthreads();
    }
    int cbase = scn[0];
    int cnt_b = bcnt[b];
    __syncthreads();

    cnt[t] = 0;
    __syncthreads();
    size_t plo = (size_t)b * BUCKET_CAP;
    for (int e = t; e < cnt_b; e += 256)
        atomicAdd(&cnt[pairs[plo + e] >> 24], 1);
    __syncthreads();
    int c = cnt[t];
    int node = b * 256 + t;
    if (node < n) dinv[node] = rsqrtf((float)(c + 1));  // +1 self-loop
    scn[t] = c;
    __syncthreads();
    for (int d = 1; d < 256; d <<= 1) {
        int xv = (t >= d) ? scn[t - d] : 0;
        __syncthreads();
        scn[t] += xv;
        __syncthreads();
    }
    int myoff = cbase + scn[t] - c;
    if (node < n) offs[node] = myoff;
    if (b == NB - 1 && t == 255) offs[n] = E;
    cnt[t] = myoff;
    __syncthreads();
    for (int e = t; e < cnt_b; e += 256) {
        unsigned p = pairs[plo + e];
        int pos = atomicAdd(&cnt[p >> 24], 1);
        csc[pos] = (int)(p & 0x00FFFFFFu);
    }
}

// ---------------------------------------------------------------- MFMA GEMMs
// mfma_f32_16x16x32_f16 layouts (gfx950). Block = 4 waves x 16 rows.
// W^T in LDS, XOR-swizzled by (col&7). Row-major fp16 intermediates.

__global__ __launch_bounds__(256) void gemm1_mfma(const float* __restrict__ X,
                                                  const __half* __restrict__ Wt,  // [128][128] f16
                                                  const float* __restrict__ dinv,
                                                  __half* __restrict__ H, int nrows) {
    __shared__ half8 wt[2048];  // 32 KB
    const int t = threadIdx.x;

    const half8* Wg = reinterpret_cast<const half8*>(Wt);
    for (int i = t; i < 2048; i += 256) {
        int col = i >> 4, kc = i & 15;
        wt[(col << 4) | (kc ^ (col & 7))] = Wg[i];
    }

    const int wid = t >> 6, lane = t & 63;
    const int li = lane & 15, kq = lane >> 4;
    const int rbase = blockIdx.x * 64 + wid * 16;
    int row = rbase + li;
    int rowc = min(row, nrows - 1);

    const f32x4* X4 = reinterpret_cast<const f32x4*>(X) + (size_t)rowc * 32;
    half8 a[4];
#pragma unroll
    for (int kk = 0; kk < 4; ++kk) {
        f32x4 lo = __builtin_nontemporal_load(&X4[kk * 8 + kq * 2]);
        f32x4 hi = __builtin_nontemporal_load(&X4[kk * 8 + kq * 2 + 1]);
        half8 v;
        v[0] = (_Float16)lo[0]; v[1] = (_Float16)lo[1];
        v[2] = (_Float16)lo[2]; v[3] = (_Float16)lo[3];
        v[4] = (_Float16)hi[0]; v[5] = (_Float16)hi[1];
        v[6] = (_Float16)hi[2]; v[7] = (_Float16)hi[3];
        a[kk] = v;
    }
    __syncthreads();

    f32x4 acc[8];
#pragma unroll
    for (int ct = 0; ct < 8; ++ct) acc[ct] = (f32x4){0.f, 0.f, 0.f, 0.f};

#pragma unroll
    for (int ct = 0; ct < 8; ++ct) {
        int col = ct * 16 + li;
        int cbase = col << 4, sw = col & 7;
#pragma unroll
        for (int kk = 0; kk < 4; ++kk) {
            half8 b = wt[cbase | ((kk * 4 + kq) ^ sw)];
            acc[ct] = __builtin_amdgcn_mfma_f32_16x16x32_f16(a[kk], b, acc[ct], 0, 0, 0);
        }
    }

    const int r0 = rbase + kq * 4;
#pragma unroll
    for (int r = 0; r < 4; ++r) {
        int rr = r0 + r;
        if (rr < nrows) {
            float s = dinv[rr];
            __half* orow = H + (size_t)rr * 128;
#pragma unroll
            for (int ct = 0; ct < 8; ++ct)
                orow[ct * 16 + li] = __float2half(acc[ct][r] * s);
        }
    }
}

__global__ __launch_bounds__(256) void gemm2_mfma(const __half* __restrict__ Xh,
                                                  const __half* __restrict__ Wt,  // [64][128] f16
                                                  const float* __restrict__ dinv,
                                                  __half* __restrict__ H, int nrows) {
    __shared__ half8 wt[1024];  // 16 KB
    const int t = threadIdx.x;

    const half8* Wg = reinterpret_cast<const half8*>(Wt);
    for (int i = t; i < 1024; i += 256) {
        int col = i >> 4, kc = i & 15;
        wt[(col << 4) | (kc ^ (col & 7))] = Wg[i];
    }

    const int wid = t >> 6, lane = t & 63;
    const int li = lane & 15, kq = lane >> 4;
    const int rbase = blockIdx.x * 64 + wid * 16;
    int row = rbase + li;
    int rowc = min(row, nrows - 1);

    const half8* A8 = reinterpret_cast<const half8*>(Xh) + (size_t)rowc * 16;
    half8 a[4];
#pragma unroll
    for (int kk = 0; kk < 4; ++kk) a[kk] = A8[kk * 4 + kq];
    __syncthreads();

    f32x4 acc[4];
#pragma unroll
    for (int ct = 0; ct < 4; ++ct) acc[ct] = (f32x4){0.f, 0.f, 0.f, 0.f};

#pragma unroll
    for (int ct = 0; ct < 4; ++ct) {
        int col = ct * 16 + li;
        int cbase = col << 4, sw = col & 7;
#pragma unroll
        for (int kk = 0; kk < 4; ++kk) {
            half8 b = wt[cbase | ((kk * 4 + kq) ^ sw)];
            acc[ct] = __builtin_amdgcn_mfma_f32_16x16x32_f16(a[kk], b, acc[ct], 0, 0, 0);
        }
    }

    const int r0 = rbase + kq * 4;
#pragma unroll
    for (int r = 0; r < 4; ++r) {
        int rr = r0 + r;
        if (rr < nrows) {
            float s = dinv[rr];
            __half* orow = H + (size_t)rr * 64;
#pragma unroll
            for (int ct = 0; ct < 4; ++ct)
                orow[ct * 16 + li] = __float2half(acc[ct][r] * s);
        }
    }
}

// ---------------------------------------------------------------- aggregation
// One wave per node; lanes 0-31 gather edge e, lanes 32-63 edge e+1.
// Scalar index loads via readfirstlane'd offsets; 32-bit saddr+voffset
// gathers; 8 edges (4 loads/lane) per main-loop iteration. [r6 measured best]

__global__ __launch_bounds__(256) void k_agg1(const __half* __restrict__ h,
                                              const int* __restrict__ offs,
                                              const int* __restrict__ csc,
                                              const float* __restrict__ dinv,
                                              const float* __restrict__ bias,
                                              __half* __restrict__ out, int n) {
    int node = (blockIdx.x * 256 + threadIdx.x) >> 6;
    if (node >= n) return;
    int lane = threadIdx.x & 63;
    int g = lane >> 5, li = lane & 31;            // li covers cols 4li..4li+3
    const char* hb = reinterpret_cast<const char*>(h);  // row = 256 B
    const unsigned loff = (unsigned)li << 3;
    int start = __builtin_amdgcn_readfirstlane(offs[node]);
    int end   = __builtin_amdgcn_readfirstlane(offs[node + 1]);
    float4 acc = make_float4(0.f, 0.f, 0.f, 0.f);

    int e = start;
    int emain = start + ((end - start) & ~7);
    for (; e < emain; e += 8) {
        int a0 = csc[e],     a1 = csc[e + 1], a2 = csc[e + 2], a3 = csc[e + 3];
        int a4 = csc[e + 4], a5 = csc[e + 5], a6 = csc[e + 6], a7 = csc[e + 7];
        unsigned o0 = (((unsigned)(g ? a1 : a0)) << 8) | loff;
        unsigned o1 = (((unsigned)(g ? a3 : a2)) << 8) | loff;
        unsigned o2 = (((unsigned)(g ? a5 : a4)) << 8) | loff;
        unsigned o3 = (((unsigned)(g ? a7 : a6)) << 8) | loff;
        uint2 v0 = ld8(hb, o0);
        uint2 v1 = ld8(hb, o1);
        uint2 v2 = ld8(hb, o2);
        uint2 v3 = ld8(hb, o3);
        acc8(acc, v0); acc8(acc, v1); acc8(acc, v2); acc8(acc, v3);
    }
    for (; e < end; e += 2) {
        int sa = csc[e];
        int sb = (e + 1 < end) ? csc[e + 1] : sa;
        unsigned o = (((unsigned)(g ? sb : sa)) << 8) | loff;
        uint2 v = ld8(hb, o);
        if (g && (e + 1 >= end)) { v.x = 0u; v.y = 0u; }
        acc8(acc, v);
    }
    acc.x += __shfl_xor(acc.x, 32);
    acc.y += __shfl_xor(acc.y, 32);
    acc.z += __shfl_xor(acc.z, 32);
    acc.w += __shfl_xor(acc.w, 32);
    uint2 vs = ld8(hb, (((unsigned)node) << 8) | loff);  // self loop
    acc8(acc, vs);
    float di = dinv[node];
    float4 bb = reinterpret_cast<const float4*>(bias)[li];
    float ox = fmaxf(fmaf(acc.x, di, bb.x), 0.f);
    float oy = fmaxf(fmaf(acc.y, di, bb.y), 0.f);
    float oz = fmaxf(fmaf(acc.z, di, bb.z), 0.f);
    float ow = fmaxf(fmaf(acc.w, di, bb.w), 0.f);
    if (g == 0)
        reinterpret_cast<uint2*>(out)[(size_t)node * 32 + li] =
            make_uint2(pack_half2(ox, oy), pack_half2(oz, ow));
}

__global__ __launch_bounds__(256) void k_agg2(const __half* __restrict__ h,
                                              const int* __restrict__ offs,
                                              const int* __restrict__ csc,
                                              const float* __restrict__ dinv,
                                              const float* __restrict__ bias,
                                              float* __restrict__ out, int n) {
    int node = (blockIdx.x * 256 + threadIdx.x) >> 6;
    if (node >= n) return;
    int lane = threadIdx.x & 63;
    int g = lane >> 5, li = lane & 31;            // li covers cols 2li..2li+1
    const char* hb = reinterpret_cast<const char*>(h);  // row = 128 B
    const unsigned loff = (unsigned)li << 2;
    int start = __builtin_amdgcn_readfirstlane(offs[node]);
    int end   = __builtin_amdgcn_readfirstlane(offs[node + 1]);
    float2 acc = make_float2(0.f, 0.f);

    int e = start;
    int emain = start + ((end - start) & ~7);
    for (; e < emain; e += 8) {
        int a0 = csc[e],     a1 = csc[e + 1], a2 = csc[e + 2], a3 = csc[e + 3];
        int a4 = csc[e + 4], a5 = csc[e + 5], a6 = csc[e + 6], a7 = csc[e + 7];
        unsigned o0 = (((unsigned)(g ? a1 : a0)) << 7) | loff;
        unsigned o1 = (((unsigned)(g ? a3 : a2)) << 7) | loff;
        unsigned o2 = (((unsigned)(g ? a5 : a4)) << 7) | loff;
        unsigned o3 = (((unsigned)(g ? a7 : a6)) << 7) | loff;
        unsigned v0 = ld4(hb, o0);
        unsigned v1 = ld4(hb, o1);
        unsigned v2 = ld4(hb, o2);
        unsigned v3 = ld4(hb, o3);
        acc4(acc, v0); acc4(acc, v1); acc4(acc, v2); acc4(acc, v3);
    }
    for (; e < end; e += 2) {
        int sa = csc[e];
        int sb = (e + 1 < end) ? csc[e + 1] : sa;
        unsigned o = (((unsigned)(g ? sb : sa)) << 7) | loff;
        unsigned v = ld4(hb, o);
        if (g && (e + 1 >= end)) v = 0u;
        acc4(acc, v);
    }
    acc.x += __shfl_xor(acc.x, 32);
    acc.y += __shfl_xor(acc.y, 32);
    acc4(acc, ld4(hb, (((unsigned)node) << 7) | loff));  // self loop
    float di = dinv[node];
    float2 bb = reinterpret_cast<const float2*>(bias)[li];
    if (g == 0)
        reinterpret_cast<float2*>(out)[(size_t)node * 32 + li] =
            make_float2(fmaf(acc.x, di, bb.x), fmaf(acc.y, di, bb.y));
}

// ---------------------------------------------------------------- launch

extern "C" void kernel_launch(void* const* d_in, const int* in_sizes, int n_in,
                              void* d_out, int out_size, void* d_ws, size_t ws_size,
                              hipStream_t stream) {
    const float* x  = (const float*)d_in[0];
    const int*   ei = (const int*)d_in[1];
    const float* W1 = (const float*)d_in[2];
    const float* b1 = (const float*)d_in[3];
    const float* W2 = (const float*)d_in[4];
    const float* b2 = (const float*)d_in[5];
    float* out = (float*)d_out;

    const int n = in_sizes[0] / 128;   // 100000 (< 2^24: packed pairs valid)
    const int E = in_sizes[1] / 2;     // 1600000
    const int* src = ei;
    const int* dst = ei + E;
    const int NB = (n + 255) / 256;    // 391 buckets of 256 nodes

    char* p = (char*)d_ws;
    auto carve = [&](size_t bytes) -> void* {
        void* r = (void*)p;
        p += (bytes + 255) & ~(size_t)255;
        return r;
    };
    float* dinv    = (float*)carve((size_t)n * 4);
    int*   offs    = (int*)carve((size_t)(n + 1) * 4);
    int*   bcnt    = (int*)carve((size_t)(NB + 1) * 4);
    __half* Wt1h   = (__half*)carve(16384 * 2);
    __half* Wt2h   = (__half*)carve(8192 * 2);
    int*   csc     = (int*)carve((size_t)E * 4);
    __half* h1     = (__half*)carve((size_t)n * 128 * 2);   // 25.6 MB
    __half* out1   = (__half*)carve((size_t)n * 128 * 2);   // 25.6 MB
    unsigned* pairs = (unsigned*)h1;  // 12.8 MB <= 25.6; dead before gemm1
    __half* h2     = h1;              // h1 dead after layer-1 aggregation

    const int gmm  = (n + 63) / 64;
    const int gagg = (n + 3) / 4;
    const int GB   = 256;                 // bucket-pass blocks (r10-proven)
    const int epb  = (E + GB - 1) / GB;   // 6250 edges per block

    // ---- init ----
    k_wconv<<<96, 256, 0, stream>>>(W1, W2, Wt1h, Wt2h, bcnt, NB + 1);

    // ---- CSC build ----
    k_bscatter2<<<GB, 256, 0, stream>>>(src, dst, E, bcnt, pairs, NB, epb);
    k_bfinal2<<<NB, 256, 0, stream>>>(pairs, bcnt, dinv, offs, csc, n, E, NB);

    // ---- layer 1: h1 = f16((x @ W1) * dinv) ; out1 = f16(relu(agg*dinv + b1)) ----
    gemm1_mfma<<<gmm, 256, 0, stream>>>(x, Wt1h, dinv, h1, n);
    k_agg1<<<gagg, 256, 0, stream>>>(h1, offs, csc, dinv, b1, out1, n);

    // ---- layer 2: h2 = f16((out1 @ W2) * dinv) ; out = agg*dinv + b2 ----
    gemm2_mfma<<<gmm, 256, 0, stream>>>(out1, Wt2h, dinv, h2, n);
    k_agg2<<<gagg, 256, 0, stream>>>(h2, offs, csc, dinv, b2, out, n);
}